// Round 6
// baseline (942.543 us; speedup 1.0000x reference)
//
#include <hip/hip_runtime.h>
#include <stdint.h>

#define N_NODES  (1u << 20)      // 1048576
#define N_EDGES  (1u << 24)      // 16777216
#define N_GRAPHS 64
#define CHUNK    (N_NODES / N_GRAPHS)  // 16384
#define K_HOPS   4

// ---- pass-1 geometry ----
#define NBLK_SS  1024            // sort blocks
#define TB_SS    1024            // sort threads
#define EPT      16              // edges per thread
#define EPB_SS   (TB_SS * EPT)   // 16384 edges per block

// ---- v1 (1024 col-buckets) fallback ----
#define NBUCKET  1024
#define CPB      1024
#define CAP      18432           // v1 slots per segment

// ---- v6 (128 col-buckets × 16 row-shards = 2048 tiles) ----
#define NBKT3    128             // col buckets (8192 cols each)
#define CPB3     8192
#define SH3      16              // row shards (65536 rows each)
#define NTILE3   (NBKT3 * SH3)   // 2048 tiles, ~8192 entries each
#define CAP3     9216            // λ=8192 +11σ
#define GRP3     4               // shard-groups per bucket (4 shards each)
#define NBLK_H3  (NBKT3 * GRP3)  // 512 hop blocks -> 2 per CU
#define NSUB     16              // sub-slices (4096 rows) per tile
// entry = (row & 0xFFFF) << 13 | (col & 0x1FFF)   (29 bits)
// tile  = (col >> 13) << 4 | (row >> 16)          (11 bits)
// in-tile sort key = entry >> 20 = row_rel >> 7   (9 bits, 512 ranges of 128 rows)
// sub-slice u = ranges [u*32, (u+1)*32)

typedef uint32_t u32x4 __attribute__((ext_vector_type(4)));
typedef unsigned long long u64x2 __attribute__((ext_vector_type(2)));
typedef float f32x4 __attribute__((ext_vector_type(4)));

__device__ __forceinline__ u32x4 nt_load_u32x4(const uint32_t* p) {
    return __builtin_nontemporal_load((const u32x4*)p);
}
__device__ __forceinline__ u64x2 nt_load_u64x2(const unsigned long long* p) {
    return __builtin_nontemporal_load((const u64x2*)p);
}
__device__ __forceinline__ void nt_store_u32x4(uint32_t* p, u32x4 v) {
    __builtin_nontemporal_store(v, (u32x4*)p);
}

// ---------------------------------------------------------------------------
// v6 pass 1: block counting sort of 16384 edges into 2048 (bucket,shard)
// tiles. Rows AND cols loaded up front; dtype detected via odd u32 words.
__global__ __launch_bounds__(TB_SS, 1)
void tile_sort3_kernel(const void* __restrict__ ei,
                       int* __restrict__ cursor, uint32_t* __restrict__ packed) {
    __shared__ uint32_t sorted[EPB_SS];   // 64 KB
    __shared__ int h[NTILE3];             // 8 KB
    __shared__ int o[NTILE3];             // 8 KB
    __shared__ int ostart[NTILE3];        // 8 KB
    __shared__ int gbase[NTILE3];         // 8 KB
    __shared__ int s_is64;
    int blk = blockIdx.x, tid = threadIdx.x;
    h[tid] = 0; h[tid + 1024] = 0;
    size_t base = (size_t)blk * EPB_SS;

    if (tid < 64) {
        size_t widx = 2 * base + 2 * (size_t)tid * (EPB_SS / 64) + 1;
        int nz = (((const uint32_t*)ei)[widx] != 0u);
        unsigned long long m = __ballot(nz);
        if (tid == 0) s_is64 = (m == 0ull) ? 1 : 0;
    }
    __syncthreads();
    int is64 = s_is64;
    uint32_t c_[EPT], r_[EPT];

    if (is64) {
        const unsigned long long* cp = (const unsigned long long*)ei + N_EDGES + base;
        const unsigned long long* rp = (const unsigned long long*)ei + base;
        #pragma unroll
        for (int it = 0; it < EPT / 4; ++it) {
            size_t i = (size_t)it * (TB_SS * 4) + (size_t)tid * 4;
            u64x2 ca = nt_load_u64x2(cp + i);
            u64x2 cb = nt_load_u64x2(cp + i + 2);
            u64x2 ra = nt_load_u64x2(rp + i);
            u64x2 rb = nt_load_u64x2(rp + i + 2);
            c_[it * 4 + 0] = (uint32_t)ca.x;  c_[it * 4 + 1] = (uint32_t)ca.y;
            c_[it * 4 + 2] = (uint32_t)cb.x;  c_[it * 4 + 3] = (uint32_t)cb.y;
            r_[it * 4 + 0] = (uint32_t)ra.x;  r_[it * 4 + 1] = (uint32_t)ra.y;
            r_[it * 4 + 2] = (uint32_t)rb.x;  r_[it * 4 + 3] = (uint32_t)rb.y;
            #pragma unroll
            for (int j = 0; j < 4; ++j) {
                int k = it * 4 + j;
                atomicAdd(&h[((c_[k] >> 13) << 4) | (r_[k] >> 16)], 1);
            }
        }
    } else {
        const uint32_t* cp = (const uint32_t*)ei + N_EDGES + base;
        const uint32_t* rp = (const uint32_t*)ei + base;
        #pragma unroll
        for (int it = 0; it < EPT / 4; ++it) {
            size_t i = (size_t)it * (TB_SS * 4) + (size_t)tid * 4;
            u32x4 a = nt_load_u32x4(cp + i);
            u32x4 r = nt_load_u32x4(rp + i);
            c_[it * 4 + 0] = a.x; c_[it * 4 + 1] = a.y;
            c_[it * 4 + 2] = a.z; c_[it * 4 + 3] = a.w;
            r_[it * 4 + 0] = r.x; r_[it * 4 + 1] = r.y;
            r_[it * 4 + 2] = r.z; r_[it * 4 + 3] = r.w;
            #pragma unroll
            for (int j = 0; j < 4; ++j) {
                int k = it * 4 + j;
                atomicAdd(&h[((c_[k] >> 13) << 4) | (r_[k] >> 16)], 1);
            }
        }
    }
    __syncthreads();

    // wave 0 exclusive-scans h[2048] (32 per lane).
    if (tid < 64) {
        int b32 = tid * 32;
        int s = 0;
        #pragma unroll
        for (int j = 0; j < 32; ++j) s += h[b32 + j];
        int v = s;
        #pragma unroll
        for (int off = 1; off < 64; off <<= 1) {
            int up = __shfl_up(v, off, 64);
            if (tid >= off) v += up;
        }
        int run = v - s;
        #pragma unroll
        for (int j = 0; j < 32; ++j) {
            o[b32 + j] = run;
            ostart[b32 + j] = run;
            run += h[b32 + j];
        }
    }
    __syncthreads();

    gbase[tid] = atomicAdd(&cursor[tid], h[tid]);
    gbase[tid + 1024] = atomicAdd(&cursor[tid + 1024], h[tid + 1024]);

    #pragma unroll
    for (int k = 0; k < EPT; ++k) {
        uint32_t c = c_[k], r = r_[k];
        int key = ((c >> 13) << 4) | (r >> 16);
        int pos = atomicAdd(&o[key], 1);
        sorted[pos] = ((r & 0xFFFFu) << 13) | (c & 0x1FFFu);
    }
    __syncthreads();

    int wave = tid >> 6, lane = tid & 63;
    for (int k = 0; k < NTILE3 / 16; ++k) {
        int b = wave * (NTILE3 / 16) + k;
        int st = ostart[b];
        int len = o[b] - st;
        int gb = gbase[b];
        if (gb + len > CAP3) len = CAP3 - gb > 0 ? CAP3 - gb : 0;
        uint32_t* dst = packed + (size_t)b * CAP3 + gb;
        for (int j = lane; j < len; j += 64)
            dst[j] = sorted[st + j];
    }
}

// ---------------------------------------------------------------------------
// v6 pass 2: per-tile in-LDS counting sort by row range (entry>>20, 512
// ranges of 128 rows). Exports 16 sub-slice starts (every 32 ranges = 4096
// rows) to bnd. LDS = 38 KB -> 4 blocks/CU.
__global__ __launch_bounds__(512)
void tile_rowsort3_kernel(uint32_t* __restrict__ packed, const int* __restrict__ cursor,
                          int* __restrict__ bnd) {
    __shared__ uint32_t sbuf[CAP3];     // 36 KB
    __shared__ int ro[512];             // 2 KB
    int t = blockIdx.x, tid = threadIdx.x;
    ro[tid] = 0;                        // blockDim 512 covers all
    __syncthreads();
    int cnt = cursor[t]; if (cnt > CAP3) cnt = CAP3;
    uint32_t* seg = packed + (size_t)t * CAP3;
    int nq = cnt >> 2;

    for (int g = tid; g < nq; g += 512) {
        u32x4 v = *(const u32x4*)(seg + 4 * (size_t)g);
        atomicAdd(&ro[v.x >> 20], 1);
        atomicAdd(&ro[v.y >> 20], 1);
        atomicAdd(&ro[v.z >> 20], 1);
        atomicAdd(&ro[v.w >> 20], 1);
    }
    {
        int tt = (nq << 2) + tid;
        if (tt < cnt) atomicAdd(&ro[seg[tt] >> 20], 1);
    }
    __syncthreads();

    if (tid < 64) {
        int b8 = tid * 8;
        int s = 0;
        #pragma unroll
        for (int j = 0; j < 8; ++j) s += ro[b8 + j];
        int v = s;
        #pragma unroll
        for (int off = 1; off < 64; off <<= 1) {
            int up = __shfl_up(v, off, 64);
            if (tid >= off) v += up;
        }
        int run = v - s;
        #pragma unroll
        for (int j = 0; j < 8; ++j) { int c = ro[b8 + j]; ro[b8 + j] = run; run += c; }
    }
    __syncthreads();

    if (tid < NSUB) bnd[t * NSUB + tid] = ro[tid * 32];
    __syncthreads();

    for (int g = tid; g < nq; g += 512) {
        u32x4 v = *(const u32x4*)(seg + 4 * (size_t)g);
        { int p = atomicAdd(&ro[v.x >> 20], 1); sbuf[p] = v.x; }
        { int p = atomicAdd(&ro[v.y >> 20], 1); sbuf[p] = v.y; }
        { int p = atomicAdd(&ro[v.z >> 20], 1); sbuf[p] = v.z; }
        { int p = atomicAdd(&ro[v.w >> 20], 1); sbuf[p] = v.w; }
    }
    {
        int tt = (nq << 2) + tid;
        if (tt < cnt) { uint32_t p = seg[tt]; int q = atomicAdd(&ro[p >> 20], 1); sbuf[q] = p; }
    }
    __syncthreads();

    for (int g = tid; g < nq; g += 512) {
        u32x4 o4;
        o4.x = sbuf[4 * g + 0]; o4.y = sbuf[4 * g + 1];
        o4.z = sbuf[4 * g + 2]; o4.w = sbuf[4 * g + 3];
        nt_store_u32x4(seg + 4 * (size_t)g, o4);
    }
    {
        int tt = (nq << 2) + tid;
        if (tt < cnt) __builtin_nontemporal_store(sbuf[tt], seg + tt);
    }
}

// ---------------------------------------------------------------------------
// Degree via LDS counting: block = (bucket, shard-group of 4). fc[8192] in
// LDS (32 KB -> 4 blocks/CU), coalesced-atomic flush into degf.
__global__ __launch_bounds__(512)
void count3_kernel(const uint32_t* __restrict__ packed, const int* __restrict__ cursor,
                   float* __restrict__ degf) {
    __shared__ float fc[CPB3];      // 32 KB
    int blk = blockIdx.x, tid = threadIdx.x;
    int bucket = blk >> 2, grp = blk & 3;
    for (int l = tid; l < CPB3; l += 512) fc[l] = 0.0f;
    __syncthreads();
    for (int s = 0; s < 4; ++s) {
        int tile = (bucket << 4) | (grp * 4 + s);
        int cnt = cursor[tile]; if (cnt > CAP3) cnt = CAP3;
        const uint32_t* seg = packed + (size_t)tile * CAP3;
        int nq = cnt >> 2;
        for (int g = tid; g < nq; g += 512) {
            u32x4 v = nt_load_u32x4(seg + 4 * (size_t)g);
            atomicAdd(&fc[v.x & 0x1FFFu], 1.0f);
            atomicAdd(&fc[v.y & 0x1FFFu], 1.0f);
            atomicAdd(&fc[v.z & 0x1FFFu], 1.0f);
            atomicAdd(&fc[v.w & 0x1FFFu], 1.0f);
        }
        int tt = (nq << 2) + tid;
        if (tt < cnt) atomicAdd(&fc[seg[tt] & 0x1FFFu], 1.0f);
    }
    __syncthreads();
    float* db = degf + ((size_t)bucket << 13);
    for (int l = tid; l < CPB3; l += 512)
        atomicAdd(&db[l], fc[l]);
}

// dinv = rsqrt(deg+1), z = dinv * x (vectorized).
__global__ __launch_bounds__(512)
void dinvz_kernel(const float* __restrict__ degf, const float* __restrict__ x,
                  float* __restrict__ dinv, float* __restrict__ z) {
    int i = blockIdx.x * 512 + threadIdx.x;
    int v0 = i << 2;
    f32x4 dg = *(const f32x4*)(degf + v0);
    f32x4 xx = *(const f32x4*)(x + v0);
    f32x4 dd, zz;
    dd.x = (float)(1.0 / sqrt((double)dg.x + 1.0));
    dd.y = (float)(1.0 / sqrt((double)dg.y + 1.0));
    dd.z = (float)(1.0 / sqrt((double)dg.z + 1.0));
    dd.w = (float)(1.0 / sqrt((double)dg.w + 1.0));
    zz = dd * xx;
    *(f32x4*)(dinv + v0) = dd;
    *(f32x4*)(z + v0) = zz;
}

// ---------------------------------------------------------------------------
// v6 hop: pure-LDS per-edge processing with a REAL software pipeline.
// Block = (bucket of 8192 cols, group of 4 shards). 64 phases of 4096-row
// sub-slices; zs double-buffered (2x16 KB), entries ride in registers
// (3/thread + rare global tail). Loads for phase p+2 are issued while phase
// p is processed -> one full phase of latency hiding. facc 32 KB.
// Total LDS 64.5 KB -> 2 blocks/CU.
__global__ __launch_bounds__(512, 2)
void hop3_kernel(const uint32_t* __restrict__ packed, const int* __restrict__ cursor,
                 const int* __restrict__ bnd, const float* __restrict__ z,
                 float* __restrict__ acc) {
    __shared__ float facc[CPB3];        // 32 KB
    __shared__ float zs[2][4096];       // 32 KB
    int blk = blockIdx.x, tid = threadIdx.x;
    int bucket = blk >> 2, grp = blk & 3;
    for (int l = tid; l < CPB3; l += 512) facc[l] = 0.0f;

#define STAGE6(P, Z0r, Z1r, E0r, E1r, E2r, stv, env, segv)                    \
    {                                                                         \
        int ph_ = (P);                                                        \
        int sh_ = grp * 4 + (ph_ >> 4);                                       \
        int sub_ = ph_ & 15;                                                  \
        int tile_ = (bucket << 4) | sh_;                                      \
        segv = packed + (size_t)tile_ * CAP3;                                 \
        stv = bnd[tile_ * NSUB + sub_];                                       \
        if (sub_ == 15) { int c_ = cursor[tile_]; env = c_ > CAP3 ? CAP3 : c_; } \
        else env = bnd[tile_ * NSUB + sub_ + 1];                              \
        const float* zg_ = z + ((size_t)sh_ << 16) + ((size_t)sub_ << 12);    \
        Z0r = *(const f32x4*)(zg_ + 4 * tid);                                 \
        Z1r = *(const f32x4*)(zg_ + 4 * (512 + tid));                         \
        int j_ = stv + tid;                                                   \
        E0r = (j_ < env) ? segv[j_] : 0xFFFFFFFFu;                            \
        E1r = (j_ + 512 < env) ? segv[j_ + 512] : 0xFFFFFFFFu;                \
        E2r = (j_ + 1024 < env) ? segv[j_ + 1024] : 0xFFFFFFFFu;              \
    }

#define WRITEZS6(buf, Z0r, Z1r)                                               \
    { *(f32x4*)(zs[buf] + 4 * tid) = Z0r;                                     \
      *(f32x4*)(zs[buf] + 4 * (512 + tid)) = Z1r; }

#define PROCESS6(buf, E0r, E1r, E2r, stv, env, segv)                          \
    { if (E0r != 0xFFFFFFFFu) atomicAdd(&facc[E0r & 8191u], zs[buf][(E0r >> 13) & 4095u]); \
      if (E1r != 0xFFFFFFFFu) atomicAdd(&facc[E1r & 8191u], zs[buf][(E1r >> 13) & 4095u]); \
      if (E2r != 0xFFFFFFFFu) atomicAdd(&facc[E2r & 8191u], zs[buf][(E2r >> 13) & 4095u]); \
      for (int j_ = stv + 1536 + tid; j_ < env; j_ += 512) {                  \
          uint32_t e_ = segv[j_];                                             \
          atomicAdd(&facc[e_ & 8191u], zs[buf][(e_ >> 13) & 4095u]); } }

    int stA, enA, stB, enB;
    const uint32_t *segA, *segB;
    f32x4 ZA0, ZA1, ZB0, ZB1;
    uint32_t EA0, EA1, EA2, EB0, EB1, EB2;

    STAGE6(0, ZA0, ZA1, EA0, EA1, EA2, stA, enA, segA);
    WRITEZS6(0, ZA0, ZA1);
    STAGE6(1, ZB0, ZB1, EB0, EB1, EB2, stB, enB, segB);
    __syncthreads();                    // zs[0] + facc init visible

    for (int ph = 0; ph < 64; ph += 2) {
        // even phase ph: data in zs[0] / A-registers
        PROCESS6(0, EA0, EA1, EA2, stA, enA, segA);
        __syncthreads();
        WRITEZS6(1, ZB0, ZB1);          // slice ph+1 (staged last iteration)
        if (ph + 2 < 64) STAGE6(ph + 2, ZA0, ZA1, EA0, EA1, EA2, stA, enA, segA);
        __syncthreads();
        // odd phase ph+1: data in zs[1] / B-registers
        PROCESS6(1, EB0, EB1, EB2, stB, enB, segB);
        __syncthreads();
        if (ph + 2 < 64) {
            WRITEZS6(0, ZA0, ZA1);      // slice ph+2
            if (ph + 3 < 64) STAGE6(ph + 3, ZB0, ZB1, EB0, EB1, EB2, stB, enB, segB);
        }
        __syncthreads();
    }

    float* ab = acc + ((size_t)bucket << 13);
    for (int l = tid; l < CPB3; l += 512)
        atomicAdd(&ab[l], facc[l]);
#undef STAGE6
#undef WRITEZS6
#undef PROCESS6
}

// merge: zout = d^2 (z + acc), re-zero acc for next hop.
__global__ __launch_bounds__(512)
void merge_mid_kernel(float* __restrict__ acc, const float* __restrict__ z,
                      const float* __restrict__ dinv, float* __restrict__ out) {
    int i = blockIdx.x * 512 + threadIdx.x;
    int v0 = i << 2;
    f32x4 aa = *(const f32x4*)(acc + v0);
    f32x4 zz = *(const f32x4*)(z + v0);
    f32x4 dd = *(const f32x4*)(dinv + v0);
    f32x4 r = dd * dd * (zz + aa);
    *(f32x4*)(out + v0) = r;
    f32x4 zero = {0.0f, 0.0f, 0.0f, 0.0f};
    *(f32x4*)(acc + v0) = zero;
}

// final merge fused with pooling: sum d*(z+acc) per 16384-node graph chunk.
__global__ __launch_bounds__(512)
void merge_final_kernel(const float* __restrict__ acc, const float* __restrict__ z,
                        const float* __restrict__ dinv, float* __restrict__ gsum) {
    __shared__ double sdata[8];
    int blk = blockIdx.x;
    int g = blk >> 3, part = blk & 7;
    int c0 = part * 2048 + (int)threadIdx.x * 4;
    int v0 = (g << 14) | c0;
    f32x4 aa = *(const f32x4*)(acc + v0);
    f32x4 zz = *(const f32x4*)(z + v0);
    f32x4 dd = *(const f32x4*)(dinv + v0);
    f32x4 val = dd * (zz + aa);
    double sl = (double)val.x + (double)val.y + (double)val.z + (double)val.w;
    #pragma unroll
    for (int off = 32; off > 0; off >>= 1) sl += __shfl_down(sl, off, 64);
    int wave = threadIdx.x >> 6, lane = threadIdx.x & 63;
    if (lane == 0) sdata[wave] = sl;
    __syncthreads();
    if (threadIdx.x == 0) {
        double tot = 0.0;
        #pragma unroll
        for (int w = 0; w < 8; ++w) tot += sdata[w];
        atomicAdd(&gsum[g], (float)tot);
    }
}

// out[g] = W * gsum[g]/CHUNK + b
__global__ void finalize_kernel(const float* __restrict__ gsum,
                                const float* __restrict__ W, const float* __restrict__ b,
                                float* __restrict__ out) {
    int g = threadIdx.x;
    if (g < N_GRAPHS)
        out[g] = (float)((double)W[0] * ((double)gsum[g] / (double)CHUNK) + (double)b[0]);
}

// ---------------------------------------------------------------------------
// v1 kernels (1024 col-buckets), mid-size-ws fallback.
__global__ __launch_bounds__(TB_SS, 2)
void scatter_sort_kernel(const void* __restrict__ ei,
                         int* __restrict__ cursor, uint32_t* __restrict__ packed) {
    __shared__ uint32_t sorted[EPB_SS];
    __shared__ int h[NBUCKET];
    __shared__ int o[NBUCKET];
    __shared__ int ostart[NBUCKET];
    __shared__ int gbase[NBUCKET];
    __shared__ int s_is64;
    int blk = blockIdx.x, tid = threadIdx.x;
    h[tid] = 0;
    size_t base = (size_t)blk * EPB_SS;
    if (tid < 64) {
        size_t widx = 2 * base + 2 * (size_t)tid * (EPB_SS / 64) + 1;
        int nz = (((const uint32_t*)ei)[widx] != 0u);
        unsigned long long m = __ballot(nz);
        if (tid == 0) s_is64 = (m == 0ull) ? 1 : 0;
    }
    __syncthreads();
    int is64 = s_is64;
    uint32_t c_[EPT];
    if (is64) {
        const unsigned long long* cp = (const unsigned long long*)ei + N_EDGES + base;
        #pragma unroll
        for (int it = 0; it < EPT / 4; ++it) {
            size_t i = (size_t)it * (TB_SS * 4) + (size_t)tid * 4;
            u64x2 a = nt_load_u64x2(cp + i);
            u64x2 b2 = nt_load_u64x2(cp + i + 2);
            c_[it * 4 + 0] = (uint32_t)a.x;  c_[it * 4 + 1] = (uint32_t)a.y;
            c_[it * 4 + 2] = (uint32_t)b2.x; c_[it * 4 + 3] = (uint32_t)b2.y;
            atomicAdd(&h[c_[it * 4 + 0] >> 10], 1);
            atomicAdd(&h[c_[it * 4 + 1] >> 10], 1);
            atomicAdd(&h[c_[it * 4 + 2] >> 10], 1);
            atomicAdd(&h[c_[it * 4 + 3] >> 10], 1);
        }
    } else {
        const uint32_t* cp = (const uint32_t*)ei + N_EDGES + base;
        #pragma unroll
        for (int it = 0; it < EPT / 4; ++it) {
            size_t i = (size_t)it * (TB_SS * 4) + (size_t)tid * 4;
            u32x4 a = nt_load_u32x4(cp + i);
            c_[it * 4 + 0] = a.x; c_[it * 4 + 1] = a.y;
            c_[it * 4 + 2] = a.z; c_[it * 4 + 3] = a.w;
            atomicAdd(&h[a.x >> 10], 1);
            atomicAdd(&h[a.y >> 10], 1);
            atomicAdd(&h[a.z >> 10], 1);
            atomicAdd(&h[a.w >> 10], 1);
        }
    }
    __syncthreads();
    if (tid < 64) {
        int b16 = tid * 16;
        int s = 0;
        #pragma unroll
        for (int j = 0; j < 16; ++j) s += h[b16 + j];
        int v = s;
        #pragma unroll
        for (int off = 1; off < 64; off <<= 1) {
            int up = __shfl_up(v, off, 64);
            if (tid >= off) v += up;
        }
        int run = v - s;
        #pragma unroll
        for (int j = 0; j < 16; ++j) {
            o[b16 + j] = run;
            ostart[b16 + j] = run;
            run += h[b16 + j];
        }
    }
    __syncthreads();
    gbase[tid] = atomicAdd(&cursor[tid], h[tid]);
    if (is64) {
        const unsigned long long* rp = (const unsigned long long*)ei + base;
        #pragma unroll
        for (int it = 0; it < EPT / 4; ++it) {
            size_t i = (size_t)it * (TB_SS * 4) + (size_t)tid * 4;
            u64x2 a = nt_load_u64x2(rp + i);
            u64x2 b2 = nt_load_u64x2(rp + i + 2);
            uint32_t rr[4] = {(uint32_t)a.x, (uint32_t)a.y, (uint32_t)b2.x, (uint32_t)b2.y};
            #pragma unroll
            for (int j = 0; j < 4; ++j) {
                uint32_t c = c_[it * 4 + j];
                int pos = atomicAdd(&o[c >> 10], 1);
                sorted[pos] = (rr[j] << 10) | (c & 1023u);
            }
        }
    } else {
        const uint32_t* rp = (const uint32_t*)ei + base;
        #pragma unroll
        for (int it = 0; it < EPT / 4; ++it) {
            size_t i = (size_t)it * (TB_SS * 4) + (size_t)tid * 4;
            u32x4 a = nt_load_u32x4(rp + i);
            uint32_t rr[4] = {a.x, a.y, a.z, a.w};
            #pragma unroll
            for (int j = 0; j < 4; ++j) {
                uint32_t c = c_[it * 4 + j];
                int pos = atomicAdd(&o[c >> 10], 1);
                sorted[pos] = (rr[j] << 10) | (c & 1023u);
            }
        }
    }
    __syncthreads();
    int wave = tid >> 6, lane = tid & 63;
    for (int k = 0; k < NBUCKET / 16; ++k) {
        int b = wave * (NBUCKET / 16) + k;
        int st = ostart[b];
        int len = o[b] - st;
        int gb = gbase[b];
        if (gb + len > CAP) len = CAP - gb > 0 ? CAP - gb : 0;
        uint32_t* dst = packed + (size_t)b * CAP + gb;
        for (int j = lane; j < len; j += 64)
            dst[j] = sorted[st + j];
    }
}

__global__ __launch_bounds__(512)
void degdinv_kernel(const uint32_t* __restrict__ packed, const int* __restrict__ cursor,
                    const float* __restrict__ x,
                    float* __restrict__ dinv, float* __restrict__ z) {
    __shared__ int h[CPB];
    int b = blockIdx.x, tid = threadIdx.x;
    for (int l = tid; l < CPB; l += 512) h[l] = 0;
    __syncthreads();
    int cnt = cursor[b]; if (cnt > CAP) cnt = CAP;
    const uint32_t* seg = packed + (size_t)b * CAP;
    int nq = cnt >> 2;
    for (int g = tid; g < nq; g += 512) {
        u32x4 v = nt_load_u32x4(seg + 4 * (size_t)g);
        atomicAdd(&h[v.x & 1023u], 1);
        atomicAdd(&h[v.y & 1023u], 1);
        atomicAdd(&h[v.z & 1023u], 1);
        atomicAdd(&h[v.w & 1023u], 1);
    }
    int t = (nq << 2) + tid;
    if (t < cnt) atomicAdd(&h[seg[t] & 1023u], 1);
    __syncthreads();
    for (int l = tid; l < CPB; l += 512) {
        int v = b * CPB + l;
        float d = (float)(1.0 / sqrt((double)(h[l] + 1)));
        dinv[v] = d;
        z[v] = d * x[v];
    }
}

__global__ __launch_bounds__(512)
void hop_kernel(const uint32_t* __restrict__ packed, const int* __restrict__ cursor,
                const float* __restrict__ z, const float* __restrict__ dinv,
                float* __restrict__ out) {
    __shared__ float facc[CPB];
    int b = blockIdx.x, tid = threadIdx.x;
    for (int l = tid; l < CPB; l += 512) facc[l] = 0.0f;
    __syncthreads();
    int cnt = cursor[b]; if (cnt > CAP) cnt = CAP;
    const uint32_t* seg = packed + (size_t)b * CAP;
    int nq = cnt >> 2;
    for (int g = tid; g < nq; g += 512) {
        u32x4 v = nt_load_u32x4(seg + 4 * (size_t)g);
        float z0 = z[v.x >> 10];
        float z1 = z[v.y >> 10];
        float z2 = z[v.z >> 10];
        float z3 = z[v.w >> 10];
        atomicAdd(&facc[v.x & 1023u], z0);
        atomicAdd(&facc[v.y & 1023u], z1);
        atomicAdd(&facc[v.z & 1023u], z2);
        atomicAdd(&facc[v.w & 1023u], z3);
    }
    int t = (nq << 2) + tid;
    if (t < cnt) { uint32_t p = seg[t]; atomicAdd(&facc[p & 1023u], z[p >> 10]); }
    __syncthreads();
    for (int l = tid; l < CPB; l += 512) {
        int v = b * CPB + l;
        float tt = z[v] + facc[l];
        float d = dinv[v];
        out[v] = d * d * tt;
    }
}

__global__ __launch_bounds__(512)
void hop_final_kernel(const uint32_t* __restrict__ packed, const int* __restrict__ cursor,
                      const float* __restrict__ z, const float* __restrict__ dinv,
                      float* __restrict__ gsum) {
    __shared__ float facc[CPB];
    __shared__ double sdata[8];
    int b = blockIdx.x, tid = threadIdx.x;
    for (int l = tid; l < CPB; l += 512) facc[l] = 0.0f;
    __syncthreads();
    int cnt = cursor[b]; if (cnt > CAP) cnt = CAP;
    const uint32_t* seg = packed + (size_t)b * CAP;
    int nq = cnt >> 2;
    for (int g = tid; g < nq; g += 512) {
        u32x4 v = nt_load_u32x4(seg + 4 * (size_t)g);
        float z0 = z[v.x >> 10];
        float z1 = z[v.y >> 10];
        float z2 = z[v.z >> 10];
        float z3 = z[v.w >> 10];
        atomicAdd(&facc[v.x & 1023u], z0);
        atomicAdd(&facc[v.y & 1023u], z1);
        atomicAdd(&facc[v.z & 1023u], z2);
        atomicAdd(&facc[v.w & 1023u], z3);
    }
    int t = (nq << 2) + tid;
    if (t < cnt) { uint32_t p = seg[t]; atomicAdd(&facc[p & 1023u], z[p >> 10]); }
    __syncthreads();
    double s = 0.0;
    for (int l = tid; l < CPB; l += 512) {
        int v = b * CPB + l;
        s += (double)(dinv[v] * (z[v] + facc[l]));
    }
    #pragma unroll
    for (int off = 32; off > 0; off >>= 1) s += __shfl_down(s, off, 64);
    int wave = tid >> 6, lane = tid & 63;
    if (lane == 0) sdata[wave] = s;
    __syncthreads();
    if (tid == 0) {
        double tot = 0.0;
        #pragma unroll
        for (int w = 0; w < 8; ++w) tot += sdata[w];
        atomicAdd(&gsum[b >> 4], (float)tot);
    }
}

// ---------------- fallback (push, atomics) for small ws ---------------------
__global__ void detect_kernel(const uint32_t* __restrict__ ei, int* __restrict__ flag) {
    __shared__ int any_nz;
    if (threadIdx.x == 0) any_nz = 0;
    __syncthreads();
    int nz = 0;
    for (int i = threadIdx.x; i < 32768; i += blockDim.x)
        nz |= (ei[2 * i + 1] != 0u);
    if (nz) atomicOr(&any_nz, 1);
    __syncthreads();
    if (threadIdx.x == 0) flag[0] = any_nz ? 0 : 1;
}

__global__ void zero_int_kernel(int* __restrict__ p) {
    int i = blockIdx.x * blockDim.x + threadIdx.x;
    p[i] = 0;
}

__device__ __forceinline__ int load_idx(const void* ei, int is64, size_t pos) {
    if (is64) return (int)((const unsigned long long*)ei)[pos];
    return ((const int*)ei)[pos];
}

__global__ void count_kernel(const void* __restrict__ ei, const int* __restrict__ flag,
                             int* __restrict__ deg) {
    int e = blockIdx.x * blockDim.x + threadIdx.x;
    int c = load_idx(ei, flag[0], (size_t)N_EDGES + (size_t)e);
    atomicAdd(&deg[c], 1);
}

__global__ void dinv_kernel(const int* __restrict__ deg, float* __restrict__ dinv) {
    int v = blockIdx.x * blockDim.x + threadIdx.x;
    dinv[v] = (float)(1.0 / sqrt((double)(deg[v] + 1)));
}

__global__ void prep_first2_kernel(const float* __restrict__ x, const float* __restrict__ dinv,
                                   float* __restrict__ z, float* __restrict__ acc) {
    int v = blockIdx.x * blockDim.x + threadIdx.x;
    float t = dinv[v] * x[v];
    z[v] = t;
    acc[v] = t;
}

__global__ void prep_mid_kernel(const float* __restrict__ dinv,
                                float* __restrict__ z, float* __restrict__ acc) {
    int v = blockIdx.x * blockDim.x + threadIdx.x;
    float d = dinv[v];
    float t = d * d * acc[v];
    z[v] = t;
    acc[v] = t;
}

__global__ void push_kernel(const void* __restrict__ ei, const int* __restrict__ flag,
                            const float* __restrict__ z, float* __restrict__ acc) {
    int e = blockIdx.x * blockDim.x + threadIdx.x;
    int is64 = flag[0];
    int r, c;
    if (is64) {
        const unsigned long long* p = (const unsigned long long*)ei;
        r = (int)p[e];
        c = (int)p[(size_t)N_EDGES + (size_t)e];
    } else {
        const int* p = (const int*)ei;
        r = p[e];
        c = p[(size_t)N_EDGES + (size_t)e];
    }
    __hip_atomic_fetch_add(&acc[c], z[r], __ATOMIC_RELAXED, __HIP_MEMORY_SCOPE_AGENT);
}

__global__ void final_scale_kernel(const float* __restrict__ dinv,
                                   const float* __restrict__ acc, float* __restrict__ xf) {
    int v = blockIdx.x * blockDim.x + threadIdx.x;
    xf[v] = dinv[v] * acc[v];
}

__global__ void pool_kernel(const float* __restrict__ xf,
                            const float* __restrict__ W, const float* __restrict__ b,
                            float* __restrict__ out) {
    __shared__ double sdata[256];
    int g = blockIdx.x;
    int base = g * CHUNK;
    double s = 0.0;
    for (int i = threadIdx.x; i < CHUNK; i += 256) s += (double)xf[base + i];
    sdata[threadIdx.x] = s;
    __syncthreads();
    for (int off = 128; off > 0; off >>= 1) {
        if (threadIdx.x < off) sdata[threadIdx.x] += sdata[threadIdx.x + off];
        __syncthreads();
    }
    if (threadIdx.x == 0)
        out[g] = (float)((double)W[0] * (sdata[0] / (double)CHUNK) + (double)b[0]);
}

extern "C" void kernel_launch(void* const* d_in, const int* in_sizes, int n_in,
                              void* d_out, int out_size, void* d_ws, size_t ws_size,
                              hipStream_t stream) {
    const float* x = (const float*)d_in[0];
    const void*  ei = d_in[1];
    const float* W = (const float*)d_in[2];
    const float* b = (const float*)d_in[3];
    float* out = (float*)d_out;

    char* ws = (char*)d_ws;
    const size_t MB4 = 4ull << 20;
    const size_t packed3_sz = (size_t)NTILE3 * CAP3 * 4;  // 72 MB
    const size_t packed1_sz = (size_t)NBUCKET * CAP * 4;  // 72 MB

    // v6 layout
    size_t off_cursor = 0;                        // 8 KB (2048 tiles)
    size_t off_gsum   = 8192;                     // 256 B (pad to 16K)
    size_t off_deg    = 16384;                    // 4 MB (float degf)
    size_t off_acc    = off_deg + MB4;            // 4 MB
    size_t off_dinv   = off_acc + MB4;            // 4 MB
    size_t off_za     = off_dinv + MB4;           // 4 MB
    size_t off_zb     = off_za + MB4;             // 4 MB
    size_t off_bnd    = off_zb + MB4;             // 128 KB (2048 x 16 ints)
    size_t off_packed = off_bnd + (size_t)NTILE3 * NSUB * 4;
    size_t needed_v6  = off_packed + packed3_sz;  // ~92.5 MB

    // v1 layout
    size_t off1_gsum   = NBUCKET * 4;
    size_t off1_dinv   = off1_gsum + 256;
    size_t off1_za     = off1_dinv + MB4;
    size_t off1_zb     = off1_za + MB4;
    size_t off1_packed = off1_zb + MB4;
    size_t needed_v1   = off1_packed + packed1_sz; // ~84 MB

    const int TB = 256;

    if (ws_size >= needed_v6) {
        int*      cursor = (int*)(ws + off_cursor);
        float*    gsum   = (float*)(ws + off_gsum);
        float*    degf   = (float*)(ws + off_deg);
        float*    acc    = (float*)(ws + off_acc);
        float*    dinv   = (float*)(ws + off_dinv);
        float*    za     = (float*)(ws + off_za);
        float*    zb     = (float*)(ws + off_zb);
        int*      bnd    = (int*)(ws + off_bnd);
        uint32_t* packed = (uint32_t*)(ws + off_packed);

        // zero cursor + gsum + degf + acc in one async memset
        hipMemsetAsync(ws, 0, off_acc + MB4, stream);

        tile_sort3_kernel<<<NBLK_SS, TB_SS, 0, stream>>>(ei, cursor, packed);
        tile_rowsort3_kernel<<<NTILE3, 512, 0, stream>>>(packed, cursor, bnd);
        count3_kernel<<<NBLK_H3, 512, 0, stream>>>(packed, cursor, degf);
        dinvz_kernel<<<N_NODES / 2048, 512, 0, stream>>>(degf, x, dinv, za);

        hop3_kernel<<<NBLK_H3, 512, 0, stream>>>(packed, cursor, bnd, za, acc);
        merge_mid_kernel<<<N_NODES / 2048, 512, 0, stream>>>(acc, za, dinv, zb);

        hop3_kernel<<<NBLK_H3, 512, 0, stream>>>(packed, cursor, bnd, zb, acc);
        merge_mid_kernel<<<N_NODES / 2048, 512, 0, stream>>>(acc, zb, dinv, za);

        hop3_kernel<<<NBLK_H3, 512, 0, stream>>>(packed, cursor, bnd, za, acc);
        merge_mid_kernel<<<N_NODES / 2048, 512, 0, stream>>>(acc, za, dinv, zb);

        hop3_kernel<<<NBLK_H3, 512, 0, stream>>>(packed, cursor, bnd, zb, acc);
        merge_final_kernel<<<N_GRAPHS * 8, 512, 0, stream>>>(acc, zb, dinv, gsum);

        finalize_kernel<<<1, 64, 0, stream>>>(gsum, W, b, out);
    } else if (ws_size >= needed_v1) {
        int*      cursor = (int*)(ws);
        float*    gsum   = (float*)(ws + off1_gsum);
        float*    dinv   = (float*)(ws + off1_dinv);
        float*    za     = (float*)(ws + off1_za);
        float*    zb     = (float*)(ws + off1_zb);
        uint32_t* packed = (uint32_t*)(ws + off1_packed);

        hipMemsetAsync(ws, 0, NBUCKET * 4 + 256, stream);

        scatter_sort_kernel<<<NBLK_SS, TB_SS, 0, stream>>>(ei, cursor, packed);
        degdinv_kernel<<<NBUCKET, 512, 0, stream>>>(packed, cursor, x, dinv, za);

        hop_kernel<<<NBUCKET, 512, 0, stream>>>(packed, cursor, za, dinv, zb);
        hop_kernel<<<NBUCKET, 512, 0, stream>>>(packed, cursor, zb, dinv, za);
        hop_kernel<<<NBUCKET, 512, 0, stream>>>(packed, cursor, za, dinv, zb);
        hop_final_kernel<<<NBUCKET, 512, 0, stream>>>(packed, cursor, zb, dinv, gsum);

        finalize_kernel<<<1, 64, 0, stream>>>(gsum, W, b, out);
    } else {
        // Fallback: push-based with atomics.
        int*   flag = (int*)ws;
        float* dinv = (float*)(ws + 256);
        float* za   = (float*)(ws + 256 + MB4);
        float* zb   = (float*)(ws + 256 + 2 * MB4);
        int*   deg  = (int*)(ws + 256 + 3 * MB4);

        detect_kernel<<<1, TB, 0, stream>>>((const uint32_t*)ei, flag);
        zero_int_kernel<<<N_NODES / TB, TB, 0, stream>>>(deg);
        count_kernel<<<N_EDGES / TB, TB, 0, stream>>>(ei, flag, deg);
        dinv_kernel<<<N_NODES / TB, TB, 0, stream>>>(deg, dinv);

        prep_first2_kernel<<<N_NODES / TB, TB, 0, stream>>>(x, dinv, za, zb);
        push_kernel<<<N_EDGES / TB, TB, 0, stream>>>(ei, flag, za, zb);
        for (int h = 1; h < K_HOPS; ++h) {
            prep_mid_kernel<<<N_NODES / TB, TB, 0, stream>>>(dinv, za, zb);
            push_kernel<<<N_EDGES / TB, TB, 0, stream>>>(ei, flag, za, zb);
        }
        final_scale_kernel<<<N_NODES / TB, TB, 0, stream>>>(dinv, zb, za);
        pool_kernel<<<N_GRAPHS, TB, 0, stream>>>(za, W, b, out);
    }
}

// Round 7
// 628.481 us; speedup vs baseline: 1.4997x; 1.4997x over previous
//
#include <hip/hip_runtime.h>
#include <stdint.h>

#define N_NODES  (1u << 20)      // 1048576
#define N_EDGES  (1u << 24)      // 16777216
#define N_GRAPHS 64
#define CHUNK    (N_NODES / N_GRAPHS)  // 16384
#define K_HOPS   4

#define NBUCKET  1024            // column buckets
#define CPB      1024            // cols per bucket
#define CAP      18432           // slots per bucket region (λ=16384, +16σ)

#define NBLK_SS  512             // scatter-sort blocks
#define TB_SS    1024            // scatter-sort threads
#define EPT      32              // edges per thread
#define EPB_SS   (TB_SS * EPT)   // 32768 edges per block

typedef uint32_t u32x4 __attribute__((ext_vector_type(4)));
typedef unsigned long long u64x2 __attribute__((ext_vector_type(2)));

__device__ __forceinline__ u32x4 nt_load_u32x4(const uint32_t* p) {
    return __builtin_nontemporal_load((const u32x4*)p);
}
__device__ __forceinline__ u64x2 nt_load_u64x2(const unsigned long long* p) {
    return __builtin_nontemporal_load((const u64x2*)p);
}

// ---------------------------------------------------------------------------
// Per-block LDS counting sort by bucket, then coalesced run write-out.
// Edge dtype detected per block: 64 sampled odd u32 words of its own slice —
// int64 little-endian (idx < 2^20) has all-zero odd words; int32 has random
// node indices there (P(all 64 zero) ~ (1e-6)^64 = 0).
__global__ __launch_bounds__(TB_SS, 4)
void scatter_sort_kernel(const void* __restrict__ ei,
                         int* __restrict__ cursor, uint32_t* __restrict__ packed) {
    __shared__ uint32_t sorted[EPB_SS];   // 128 KB
    __shared__ int h[NBUCKET];            // 4 KB
    __shared__ int o[NBUCKET];            // 4 KB (scan, then bumped by scatter)
    __shared__ int ostart[NBUCKET];       // 4 KB (stable run starts)
    __shared__ int gbase[NBUCKET];        // 4 KB
    __shared__ int s_is64;
    int blk = blockIdx.x, tid = threadIdx.x;
    h[tid] = 0;
    size_t base = (size_t)blk * EPB_SS;

    // dtype detection: wave 0 samples odd u32 words across this block's slice.
    if (tid < 64) {
        size_t widx = 2 * base + 2 * (size_t)tid * 512 + 1;
        int nz = (((const uint32_t*)ei)[widx] != 0u);
        unsigned long long m = __ballot(nz);
        if (tid == 0) s_is64 = (m == 0ull) ? 1 : 0;
    }
    __syncthreads();
    int is64 = s_is64;
    uint32_t c_[EPT];

    // Phase A: load cols (non-temporal stream), histogram buckets.
    if (is64) {
        const unsigned long long* cp = (const unsigned long long*)ei + N_EDGES + base;
        #pragma unroll
        for (int it = 0; it < EPT / 4; ++it) {
            size_t i = (size_t)it * (TB_SS * 4) + (size_t)tid * 4;
            u64x2 a = nt_load_u64x2(cp + i);
            u64x2 b2 = nt_load_u64x2(cp + i + 2);
            c_[it * 4 + 0] = (uint32_t)a.x;  c_[it * 4 + 1] = (uint32_t)a.y;
            c_[it * 4 + 2] = (uint32_t)b2.x; c_[it * 4 + 3] = (uint32_t)b2.y;
            atomicAdd(&h[c_[it * 4 + 0] >> 10], 1);
            atomicAdd(&h[c_[it * 4 + 1] >> 10], 1);
            atomicAdd(&h[c_[it * 4 + 2] >> 10], 1);
            atomicAdd(&h[c_[it * 4 + 3] >> 10], 1);
        }
    } else {
        const uint32_t* cp = (const uint32_t*)ei + N_EDGES + base;
        #pragma unroll
        for (int it = 0; it < EPT / 4; ++it) {
            size_t i = (size_t)it * (TB_SS * 4) + (size_t)tid * 4;
            u32x4 a = nt_load_u32x4(cp + i);
            c_[it * 4 + 0] = a.x; c_[it * 4 + 1] = a.y;
            c_[it * 4 + 2] = a.z; c_[it * 4 + 3] = a.w;
            atomicAdd(&h[a.x >> 10], 1);
            atomicAdd(&h[a.y >> 10], 1);
            atomicAdd(&h[a.z >> 10], 1);
            atomicAdd(&h[a.w >> 10], 1);
        }
    }
    __syncthreads();

    // Phase B: wave 0 exclusive-scans h[1024] -> o/ostart.
    if (tid < 64) {
        int b16 = tid * 16;
        int s = 0;
        #pragma unroll
        for (int j = 0; j < 16; ++j) s += h[b16 + j];
        int v = s;
        #pragma unroll
        for (int off = 1; off < 64; off <<= 1) {
            int up = __shfl_up(v, off, 64);
            if (tid >= off) v += up;
        }
        int run = v - s;  // exclusive
        #pragma unroll
        for (int j = 0; j < 16; ++j) {
            o[b16 + j] = run;
            ostart[b16 + j] = run;
            run += h[b16 + j];
        }
    }
    __syncthreads();

    // Per-bucket global reserve (1 atomic per bucket per block).
    gbase[tid] = atomicAdd(&cursor[tid], h[tid]);

    // Phase C: load rows (non-temporal), scatter packed entries into LDS.
    if (is64) {
        const unsigned long long* rp = (const unsigned long long*)ei + base;
        #pragma unroll
        for (int it = 0; it < EPT / 4; ++it) {
            size_t i = (size_t)it * (TB_SS * 4) + (size_t)tid * 4;
            u64x2 a = nt_load_u64x2(rp + i);
            u64x2 b2 = nt_load_u64x2(rp + i + 2);
            uint32_t r0 = (uint32_t)a.x, r1 = (uint32_t)a.y;
            uint32_t r2 = (uint32_t)b2.x, r3 = (uint32_t)b2.y;
            { uint32_t c = c_[it * 4 + 0]; int pos = atomicAdd(&o[c >> 10], 1); sorted[pos] = (r0 << 10) | (c & 1023u); }
            { uint32_t c = c_[it * 4 + 1]; int pos = atomicAdd(&o[c >> 10], 1); sorted[pos] = (r1 << 10) | (c & 1023u); }
            { uint32_t c = c_[it * 4 + 2]; int pos = atomicAdd(&o[c >> 10], 1); sorted[pos] = (r2 << 10) | (c & 1023u); }
            { uint32_t c = c_[it * 4 + 3]; int pos = atomicAdd(&o[c >> 10], 1); sorted[pos] = (r3 << 10) | (c & 1023u); }
        }
    } else {
        const uint32_t* rp = (const uint32_t*)ei + base;
        #pragma unroll
        for (int it = 0; it < EPT / 4; ++it) {
            size_t i = (size_t)it * (TB_SS * 4) + (size_t)tid * 4;
            u32x4 a = nt_load_u32x4(rp + i);
            { uint32_t c = c_[it * 4 + 0]; int pos = atomicAdd(&o[c >> 10], 1); sorted[pos] = (a.x << 10) | (c & 1023u); }
            { uint32_t c = c_[it * 4 + 1]; int pos = atomicAdd(&o[c >> 10], 1); sorted[pos] = (a.y << 10) | (c & 1023u); }
            { uint32_t c = c_[it * 4 + 2]; int pos = atomicAdd(&o[c >> 10], 1); sorted[pos] = (a.z << 10) | (c & 1023u); }
            { uint32_t c = c_[it * 4 + 3]; int pos = atomicAdd(&o[c >> 10], 1); sorted[pos] = (a.w << 10) | (c & 1023u); }
        }
    }
    __syncthreads();

    // Phase D: write-out. Wave w copies buckets [w*64, w*64+64); runs contiguous.
    int wave = tid >> 6, lane = tid & 63;
    for (int k = 0; k < NBUCKET / 16; ++k) {
        int b = wave * (NBUCKET / 16) + k;
        int st = ostart[b];
        int len = o[b] - st;
        int gb = gbase[b];
        if (gb + len > CAP) len = CAP - gb > 0 ? CAP - gb : 0;
        uint32_t* dst = packed + (size_t)b * CAP + gb;
        for (int j = lane; j < len; j += 64)
            dst[j] = sorted[st + j];
    }
}

// ---------------------------------------------------------------------------
// Per-bucket degree -> dinv, fused with z0 = dinv * x. nt streaming reads.
__global__ __launch_bounds__(512)
void degdinv_kernel(const uint32_t* __restrict__ packed, const int* __restrict__ cursor,
                    const float* __restrict__ x,
                    float* __restrict__ dinv, float* __restrict__ z) {
    __shared__ int h[CPB];
    int b = blockIdx.x, tid = threadIdx.x;
    for (int l = tid; l < CPB; l += 512) h[l] = 0;
    __syncthreads();
    int cnt = cursor[b]; if (cnt > CAP) cnt = CAP;
    const uint32_t* seg = packed + (size_t)b * CAP;
    int nq = cnt >> 2;
    for (int g = tid; g < nq; g += 512) {
        u32x4 v = nt_load_u32x4(seg + g * 4);
        atomicAdd(&h[v.x & 1023u], 1);
        atomicAdd(&h[v.y & 1023u], 1);
        atomicAdd(&h[v.z & 1023u], 1);
        atomicAdd(&h[v.w & 1023u], 1);
    }
    int t = (nq << 2) + tid;
    if (t < cnt) atomicAdd(&h[seg[t] & 1023u], 1);
    __syncthreads();
    for (int l = tid; l < CPB; l += 512) {
        int v = b * CPB + l;
        float d = (float)(1.0 / sqrt((double)(h[l] + 1)));  // +1 self loop
        dinv[v] = d;
        z[v] = d * x[v];
    }
}

// ---------------------------------------------------------------------------
// Bucketed mid hop: LDS accumulate z[row] per local col (nt on packed stream),
// then zout[v] = d^2 * (z[v] + facc).
__global__ __launch_bounds__(512)
void hop_kernel(const uint32_t* __restrict__ packed, const int* __restrict__ cursor,
                const float* __restrict__ z, const float* __restrict__ dinv,
                float* __restrict__ out) {
    __shared__ float facc[CPB];
    int b = blockIdx.x, tid = threadIdx.x;
    for (int l = tid; l < CPB; l += 512) facc[l] = 0.0f;
    __syncthreads();
    int cnt = cursor[b]; if (cnt > CAP) cnt = CAP;
    const uint32_t* seg = packed + (size_t)b * CAP;
    int nq = cnt >> 2;
    for (int g = tid; g < nq; g += 512) {
        u32x4 v = nt_load_u32x4(seg + 4 * (size_t)g);
        float z0 = z[v.x >> 10];
        float z1 = z[v.y >> 10];
        float z2 = z[v.z >> 10];
        float z3 = z[v.w >> 10];
        atomicAdd(&facc[v.x & 1023u], z0);
        atomicAdd(&facc[v.y & 1023u], z1);
        atomicAdd(&facc[v.z & 1023u], z2);
        atomicAdd(&facc[v.w & 1023u], z3);
    }
    int t = (nq << 2) + tid;
    if (t < cnt) { uint32_t p = seg[t]; atomicAdd(&facc[p & 1023u], z[p >> 10]); }
    __syncthreads();
    for (int l = tid; l < CPB; l += 512) {
        int v = b * CPB + l;
        float tt = z[v] + facc[l];
        float d = dinv[v];
        out[v] = d * d * tt;
    }
}

// ---------------------------------------------------------------------------
// Final hop fused with pooling: xf[v] = d*(z[v]+facc) reduced per block into
// one float atomicAdd into gsum[graph]. No xf write.
__global__ __launch_bounds__(512)
void hop_final_kernel(const uint32_t* __restrict__ packed, const int* __restrict__ cursor,
                      const float* __restrict__ z, const float* __restrict__ dinv,
                      float* __restrict__ gsum) {
    __shared__ float facc[CPB];
    __shared__ double sdata[8];
    int b = blockIdx.x, tid = threadIdx.x;
    for (int l = tid; l < CPB; l += 512) facc[l] = 0.0f;
    __syncthreads();
    int cnt = cursor[b]; if (cnt > CAP) cnt = CAP;
    const uint32_t* seg = packed + (size_t)b * CAP;
    int nq = cnt >> 2;
    for (int g = tid; g < nq; g += 512) {
        u32x4 v = nt_load_u32x4(seg + 4 * (size_t)g);
        float z0 = z[v.x >> 10];
        float z1 = z[v.y >> 10];
        float z2 = z[v.z >> 10];
        float z3 = z[v.w >> 10];
        atomicAdd(&facc[v.x & 1023u], z0);
        atomicAdd(&facc[v.y & 1023u], z1);
        atomicAdd(&facc[v.z & 1023u], z2);
        atomicAdd(&facc[v.w & 1023u], z3);
    }
    int t = (nq << 2) + tid;
    if (t < cnt) { uint32_t p = seg[t]; atomicAdd(&facc[p & 1023u], z[p >> 10]); }
    __syncthreads();
    double s = 0.0;
    for (int l = tid; l < CPB; l += 512) {
        int v = b * CPB + l;
        s += (double)(dinv[v] * (z[v] + facc[l]));
    }
    #pragma unroll
    for (int off = 32; off > 0; off >>= 1) s += __shfl_down(s, off, 64);
    int wave = tid >> 6, lane = tid & 63;
    if (lane == 0) sdata[wave] = s;
    __syncthreads();
    if (tid == 0) {
        double tot = 0.0;
        #pragma unroll
        for (int w = 0; w < 8; ++w) tot += sdata[w];
        atomicAdd(&gsum[b >> 4], (float)tot);   // 16 buckets per graph chunk
    }
}

// out[g] = W * gsum[g]/CHUNK + b
__global__ void finalize_kernel(const float* __restrict__ gsum,
                                const float* __restrict__ W, const float* __restrict__ b,
                                float* __restrict__ out) {
    int g = threadIdx.x;
    if (g < N_GRAPHS)
        out[g] = (float)((double)W[0] * ((double)gsum[g] / (double)CHUNK) + (double)b[0]);
}

// ---------------- fallback (push, atomics) for small ws ---------------------
__global__ void detect_kernel(const uint32_t* __restrict__ ei, int* __restrict__ flag) {
    __shared__ int any_nz;
    if (threadIdx.x == 0) any_nz = 0;
    __syncthreads();
    int nz = 0;
    for (int i = threadIdx.x; i < 32768; i += blockDim.x)
        nz |= (ei[2 * i + 1] != 0u);
    if (nz) atomicOr(&any_nz, 1);
    __syncthreads();
    if (threadIdx.x == 0) flag[0] = any_nz ? 0 : 1;
}

__global__ void zero_int_kernel(int* __restrict__ p) {
    int i = blockIdx.x * blockDim.x + threadIdx.x;
    p[i] = 0;
}

__device__ __forceinline__ int load_idx(const void* ei, int is64, size_t pos) {
    if (is64) return (int)((const unsigned long long*)ei)[pos];
    return ((const int*)ei)[pos];
}

__global__ void count_kernel(const void* __restrict__ ei, const int* __restrict__ flag,
                             int* __restrict__ deg) {
    int e = blockIdx.x * blockDim.x + threadIdx.x;
    int c = load_idx(ei, flag[0], (size_t)N_EDGES + (size_t)e);
    atomicAdd(&deg[c], 1);
}

__global__ void dinv_kernel(const int* __restrict__ deg, float* __restrict__ dinv) {
    int v = blockIdx.x * blockDim.x + threadIdx.x;
    dinv[v] = (float)(1.0 / sqrt((double)(deg[v] + 1)));
}

__global__ void prep_first2_kernel(const float* __restrict__ x, const float* __restrict__ dinv,
                                   float* __restrict__ z, float* __restrict__ acc) {
    int v = blockIdx.x * blockDim.x + threadIdx.x;
    float t = dinv[v] * x[v];
    z[v] = t;
    acc[v] = t;
}

__global__ void prep_mid_kernel(const float* __restrict__ dinv,
                                float* __restrict__ z, float* __restrict__ acc) {
    int v = blockIdx.x * blockDim.x + threadIdx.x;
    float d = dinv[v];
    float t = d * d * acc[v];
    z[v] = t;
    acc[v] = t;
}

__global__ void push_kernel(const void* __restrict__ ei, const int* __restrict__ flag,
                            const float* __restrict__ z, float* __restrict__ acc) {
    int e = blockIdx.x * blockDim.x + threadIdx.x;
    int is64 = flag[0];
    int r, c;
    if (is64) {
        const unsigned long long* p = (const unsigned long long*)ei;
        r = (int)p[e];
        c = (int)p[(size_t)N_EDGES + (size_t)e];
    } else {
        const int* p = (const int*)ei;
        r = p[e];
        c = p[(size_t)N_EDGES + (size_t)e];
    }
    __hip_atomic_fetch_add(&acc[c], z[r], __ATOMIC_RELAXED, __HIP_MEMORY_SCOPE_AGENT);
}

__global__ void final_scale_kernel(const float* __restrict__ dinv,
                                   const float* __restrict__ acc, float* __restrict__ xf) {
    int v = blockIdx.x * blockDim.x + threadIdx.x;
    xf[v] = dinv[v] * acc[v];
}

__global__ void pool_kernel(const float* __restrict__ xf,
                            const float* __restrict__ W, const float* __restrict__ b,
                            float* __restrict__ out) {
    __shared__ double sdata[256];
    int g = blockIdx.x;
    int base = g * CHUNK;
    double s = 0.0;
    for (int i = threadIdx.x; i < CHUNK; i += 256) s += (double)xf[base + i];
    sdata[threadIdx.x] = s;
    __syncthreads();
    for (int off = 128; off > 0; off >>= 1) {
        if (threadIdx.x < off) sdata[threadIdx.x] += sdata[threadIdx.x + off];
        __syncthreads();
    }
    if (threadIdx.x == 0)
        out[g] = (float)((double)W[0] * (sdata[0] / (double)CHUNK) + (double)b[0]);
}

extern "C" void kernel_launch(void* const* d_in, const int* in_sizes, int n_in,
                              void* d_out, int out_size, void* d_ws, size_t ws_size,
                              hipStream_t stream) {
    const float* x = (const float*)d_in[0];
    const void*  ei = d_in[1];
    const float* W = (const float*)d_in[2];
    const float* b = (const float*)d_in[3];
    float* out = (float*)d_out;

    char* ws = (char*)d_ws;
    const size_t MB4 = 4ull << 20;
    size_t off_cursor = 0;                                // 4 KB
    size_t off_gsum   = NBUCKET * 4;                      // 256 B
    size_t off_dinv   = off_gsum + 256;                   // 4 MB
    size_t off_za     = off_dinv + MB4;                   // 4 MB
    size_t off_zb     = off_za + MB4;                     // 4 MB
    size_t off_packed = off_zb + MB4;                     // 72 MB
    size_t needed     = off_packed + (size_t)NBUCKET * CAP * 4;

    const int TB = 256;

    if (ws_size >= needed) {
        int*      cursor = (int*)(ws + off_cursor);
        float*    gsum   = (float*)(ws + off_gsum);
        float*    dinv   = (float*)(ws + off_dinv);
        float*    za     = (float*)(ws + off_za);
        float*    zb     = (float*)(ws + off_zb);
        uint32_t* packed = (uint32_t*)(ws + off_packed);

        // zero cursor[1024] + gsum[64] in one async memset (graph-capturable)
        hipMemsetAsync(ws, 0, NBUCKET * 4 + 256, stream);

        scatter_sort_kernel<<<NBLK_SS, TB_SS, 0, stream>>>(ei, cursor, packed);
        degdinv_kernel<<<NBUCKET, 512, 0, stream>>>(packed, cursor, x, dinv, za);

        hop_kernel<<<NBUCKET, 512, 0, stream>>>(packed, cursor, za, dinv, zb);
        hop_kernel<<<NBUCKET, 512, 0, stream>>>(packed, cursor, zb, dinv, za);
        hop_kernel<<<NBUCKET, 512, 0, stream>>>(packed, cursor, za, dinv, zb);
        hop_final_kernel<<<NBUCKET, 512, 0, stream>>>(packed, cursor, zb, dinv, gsum);

        finalize_kernel<<<1, 64, 0, stream>>>(gsum, W, b, out);
    } else {
        // Fallback: push-based with atomics.
        int*   flag = (int*)ws;
        float* dinv = (float*)(ws + 256);
        float* za   = (float*)(ws + 256 + MB4);
        float* zb   = (float*)(ws + 256 + 2 * MB4);
        int*   deg  = (int*)(ws + 256 + 3 * MB4);

        detect_kernel<<<1, TB, 0, stream>>>((const uint32_t*)ei, flag);
        zero_int_kernel<<<N_NODES / TB, TB, 0, stream>>>(deg);
        count_kernel<<<N_EDGES / TB, TB, 0, stream>>>(ei, flag, deg);
        dinv_kernel<<<N_NODES / TB, TB, 0, stream>>>(deg, dinv);

        prep_first2_kernel<<<N_NODES / TB, TB, 0, stream>>>(x, dinv, za, zb);
        push_kernel<<<N_EDGES / TB, TB, 0, stream>>>(ei, flag, za, zb);
        for (int h = 1; h < K_HOPS; ++h) {
            prep_mid_kernel<<<N_NODES / TB, TB, 0, stream>>>(dinv, za, zb);
            push_kernel<<<N_EDGES / TB, TB, 0, stream>>>(ei, flag, za, zb);
        }
        final_scale_kernel<<<N_NODES / TB, TB, 0, stream>>>(dinv, zb, za);
        pool_kernel<<<N_GRAPHS, TB, 0, stream>>>(za, W, b, out);
    }
}